// Round 2
// baseline (265.316 us; speedup 1.0000x reference)
//
#include <hip/hip_runtime.h>
#include <stdint.h>

#define Bb 32
#define Ss 2048
#define Dd 128
#define KVB 64
#define NIT (Ss / KVB)   // 32

typedef __attribute__((ext_vector_type(2))) float f32x2;
typedef __attribute__((ext_vector_type(4))) float f32x4;
typedef __attribute__((ext_vector_type(16))) float f32x16;
typedef __attribute__((ext_vector_type(8))) _Float16 f16x8;
typedef __attribute__((ext_vector_type(2))) __fp16 fp16x2;
typedef __attribute__((ext_vector_type(8))) unsigned short u16x8;
typedef __attribute__((ext_vector_type(4))) unsigned short u16x4;

union F16_8 { u16x8 u; uint32_t w[4]; f16x8 h; };
union F16_4 { u16x4 u; uint32_t w[2]; };

__device__ __forceinline__ uint32_t pk2(float a, float b) {   // packed f32->f16 RTZ
    union { fp16x2 h; uint32_t u; } v;
    v.h = __builtin_amdgcn_cvt_pkrtz(a, b);
    return v.u;
}

__global__ __launch_bounds__(256) __attribute__((amdgpu_waves_per_eu(2, 2)))
void attn_fwd(const float* __restrict__ Q,
              const float* __restrict__ K,
              const float* __restrict__ V,
              const int* __restrict__ M,
              float* __restrict__ O) {
    // double-buffered K/V; maskadd 4-deep (written 2 tiles ahead)
    __shared__ unsigned short K_lds[2][KVB * 128];   // [key][d] fp16, XOR-swizzled
    __shared__ unsigned short VT_lds[2][128 * 64];   // [d][key] fp16, XOR-swizzled
    __shared__ float maskadd[4][KVB];

    const int tid = threadIdx.x;
    const int w   = tid >> 6;
    const int l   = tid & 63;
    const int q31 = l & 31;       // this lane's q-column (and LDS row index)
    const int hi  = l >> 5;

    const int bid   = blockIdx.x;
    const int batch = (bid & 7) * 4 + (bid >> 7);   // XCD-aware, bijective
    const int qtile = (bid >> 3) & 15;

    const size_t qrow0  = (size_t)batch * Ss + qtile * 128 + w * 32;
    const size_t kvbase = (size_t)batch * Ss * Dd;
    const size_t mbase  = (size_t)batch * Ss;

    // ---- staging geometry ----
    const int krow = tid >> 4;            // K: rows krow+16*it
    const int kcol = (tid & 15) << 3;     // K: 8 floats
    const int vi   = tid & 15;            // V: d-pair base (rows 2vi+p+32j)
    const int vk   = (tid >> 4) << 2;     // V: 4 keys

    f32x4 ka[4], kb[4];                   // K tile in flight
    f32x2 vv[4][4];                       // V tile in flight [j][ko]
    int mld = 0;

    auto issueK = [&](int kv) {
#pragma unroll
        for (int it = 0; it < 4; ++it) {
            const float* s = K + kvbase + (size_t)(kv + krow + it * 16) * Dd + kcol;
            ka[it] = *(const f32x4*)s;
            kb[it] = *(const f32x4*)(s + 4);
        }
        if (tid < KVB) mld = M[mbase + kv + tid];
    };
    auto writeK = [&](int bfi, int ms) {
#pragma unroll
        for (int it = 0; it < 4; ++it) {
            int row = krow + it * 16;
            F16_8 t;
            t.w[0] = pk2(ka[it][0], ka[it][1]);
            t.w[1] = pk2(ka[it][2], ka[it][3]);
            t.w[2] = pk2(kb[it][0], kb[it][1]);
            t.w[3] = pk2(kb[it][2], kb[it][3]);
            *(u16x8*)&K_lds[bfi][(row * 128 + kcol) ^ ((row & 7) << 3)] = t.u;
        }
        if (tid < KVB) maskadd[ms][tid] = mld ? 0.f : -1e30f;
    };
    auto issueV = [&](int kv) {
#pragma unroll
        for (int j = 0; j < 4; ++j)
#pragma unroll
            for (int ko = 0; ko < 4; ++ko)
                vv[j][ko] = *(const f32x2*)(V + kvbase + (size_t)(kv + vk + ko) * Dd + 2 * vi + 32 * j);
    };
    auto writeV = [&](int bfi) {
#pragma unroll
        for (int j = 0; j < 4; ++j)
#pragma unroll
            for (int p = 0; p < 2; ++p) {
                int row = 2 * vi + p + 32 * j;           // row&7 varies per lane -> conflict-free
                F16_4 t;
                t.w[0] = pk2(vv[j][0][p], vv[j][1][p]);
                t.w[1] = pk2(vv[j][2][p], vv[j][3][p]);
                *(u16x4*)&VT_lds[bfi][row * 64 + (vk ^ ((row & 7) << 3))] = t.u;
            }
    };

    // ones A-fragment (rows 0..7 = 1.0) for MFMA-computed l
    F16_8 ones;
    {
        uint32_t ow = (q31 < 8) ? 0x3C003C00u : 0u;
        ones.w[0] = ow; ones.w[1] = ow; ones.w[2] = ow; ones.w[3] = ow;
    }

    const f32x16 z16 = {0,0,0,0,0,0,0,0,0,0,0,0,0,0,0,0};
    f32x16 acco[4];                       // O^T: lane owns q=q31, rows = d
#pragma unroll
    for (int dn = 0; dn < 4; ++dn) acco[dn] = z16;
    f32x16 accl = z16;                    // l in element 0
    float mrun = -1e4f;

    // ---- prologue ----
    const float LOG2E = 1.44269504088896340736f;
    issueK(0); issueV(0);
    F16_8 qf[8];                          // Q frags, pre-scaled by log2(e)
#pragma unroll
    for (int ks = 0; ks < 8; ++ks) {
        const float* s = Q + (qrow0 + q31) * Dd + ks * 16 + hi * 8;
        f32x4 a = *(const f32x4*)s;
        f32x4 b = *(const f32x4*)(s + 4);
        qf[ks].w[0] = pk2(a[0] * LOG2E, a[1] * LOG2E);
        qf[ks].w[1] = pk2(a[2] * LOG2E, a[3] * LOG2E);
        qf[ks].w[2] = pk2(b[0] * LOG2E, b[1] * LOG2E);
        qf[ks].w[3] = pk2(b[2] * LOG2E, b[3] * LOG2E);
    }
    writeK(0, 0); writeV(0);
    issueK(KVB);                                   // K(1)+mask(1)
    __syncthreads();                               // Kbuf0/Vbuf0/mask0 visible

    f32x16 accA[2], accB[2];
    accA[0] = z16; accA[1] = z16;
#pragma unroll
    for (int ks = 0; ks < 8; ++ks)                 // QK(0) from Kbuf0
#pragma unroll
        for (int n = 0; n < 2; ++n) {
            int row = n * 32 + q31;
            F16_8 kf;
            kf.u = *(const u16x8*)&K_lds[0][(row * 128 + ks * 16 + hi * 8) ^ ((row & 7) << 3)];
            accA[n] = __builtin_amdgcn_mfma_f32_32x32x16_f16(kf.h, qf[ks].h, accA[n], 0, 0, 0);
        }
    writeK(1, 1);                                  // K(1)->Kbuf1, mask(1)
    issueK(2 * KVB); issueV(KVB);                  // staged regs for iter0 top writes
    __syncthreads();                               // Kbuf1/mask1 visible before iter0's QK(1)

    // ---- main loop: 2x unrolled body, static acc ping-pong ----
#define BODY(T, CUR, NXT, BF)                                                          \
  do {                                                                                 \
    const int t_ = (T);                                                                \
    if (t_ + 2 < NIT) writeK(BF, (t_ + 2) & 3);          /* Kbuf[BF] free since QK(t) */ \
    if (t_ + 1 < NIT) writeV(BF ^ 1);                    /* Vbuf[BF^1] free since PV(t-1) */ \
    if (t_ + 3 < NIT) issueK((t_ + 3) * KVB);                                          \
    if (t_ + 2 < NIT) issueV((t_ + 2) * KVB);                                          \
    /* mask add (broadcast f32x4) */                                                   \
    _Pragma("unroll")                                                                  \
    for (int n = 0; n < 2; ++n) {                                                      \
      _Pragma("unroll")                                                                \
      for (int blk = 0; blk < 4; ++blk) {                                              \
        f32x4 md = *(const f32x4*)&maskadd[t_ & 3][n * 32 + blk * 8 + 4 * hi];         \
        _Pragma("unroll")                                                              \
        for (int r = 0; r < 4; ++r) CUR[n][blk * 4 + r] += md[r];                      \
      }                                                                                \
    }                                                                                  \
    /* tree max, depth 5 */                                                            \
    float mx[16];                                                                      \
    _Pragma("unroll")                                                                  \
    for (int i = 0; i < 16; ++i) mx[i] = fmaxf(CUR[0][i], CUR[1][i]);                  \
    _Pragma("unroll")                                                                  \
    for (int s_ = 8; s_ >= 1; s_ >>= 1) {                                              \
      _Pragma("unroll")                                                                \
      for (int i = 0; i < s_; ++i) mx[i] = fmaxf(mx[i], mx[i + s_]);                   \
    }                                                                                  \
    float pmax = fmaxf(mx[0], __shfl_xor(mx[0], 32));                                  \
    /* defer-max rescale: threshold 8 nats = 11.54 log2-units */                       \
    if (!__all(pmax - mrun <= 11.5409f)) {                                             \
      float mnew = fmaxf(mrun, pmax);                                                  \
      float sc = exp2f(mrun - mnew);                                                   \
      _Pragma("unroll")                                                                \
      for (int dn = 0; dn < 4; ++dn) {                                                 \
        _Pragma("unroll")                                                              \
        for (int i = 0; i < 16; ++i) acco[dn][i] *= sc;                                \
      }                                                                                \
      accl[0] *= sc;                                                                   \
      mrun = mnew;                                                                     \
    }                                                                                  \
    _Pragma("unroll")                                                                  \
    for (int n = 0; n < 2; ++n) {                                                      \
      _Pragma("unroll")                                                                \
      for (int i = 0; i < 16; ++i) CUR[n][i] = exp2f(CUR[n][i] - mrun);                \
    }                                                                                  \
    /* QK(t+1) into NXT from Kbuf[BF^1] -- independent of softmax(t), scheduler overlaps */ \
    if (t_ + 1 < NIT) {                                                                \
      NXT[0] = z16; NXT[1] = z16;                                                      \
      _Pragma("unroll")                                                                \
      for (int ks = 0; ks < 8; ++ks) {                                                 \
        _Pragma("unroll")                                                              \
        for (int n = 0; n < 2; ++n) {                                                  \
          int row = n * 32 + q31;                                                      \
          F16_8 kf;                                                                    \
          kf.u = *(const u16x8*)&K_lds[BF ^ 1][(row * 128 + ks * 16 + hi * 8) ^ ((row & 7) << 3)]; \
          NXT[n] = __builtin_amdgcn_mfma_f32_32x32x16_f16(kf.h, qf[ks].h, NXT[n], 0, 0, 0); \
        }                                                                              \
      }                                                                                \
    }                                                                                  \
    /* pack P^T -> B-frags via permlane32_swap */                                      \
    F16_8 pa[4];                                                                       \
    _Pragma("unroll")                                                                  \
    for (int ks = 0; ks < 4; ++ks) {                                                   \
      int n  = ks >> 1;                                                                \
      int b4 = (ks & 1) * 8;                                                           \
      uint32_t x0 = pk2(CUR[n][b4 + 0], CUR[n][b4 + 1]);                               \
      uint32_t x1 = pk2(CUR[n][b4 + 2], CUR[n][b4 + 3]);                               \
      uint32_t y0 = pk2(CUR[n][b4 + 4], CUR[n][b4 + 5]);                               \
      uint32_t y1 = pk2(CUR[n][b4 + 6], CUR[n][b4 + 7]);                               \
      asm volatile("v_permlane32_swap_b32 %0, %1" : "+v"(x0), "+v"(y0));               \
      asm volatile("v_permlane32_swap_b32 %0, %1" : "+v"(x1), "+v"(y1));               \
      pa[ks].w[0] = x0; pa[ks].w[1] = x1; pa[ks].w[2] = y0; pa[ks].w[3] = y1;          \
    }                                                                                  \
    /* O^T += V^T . P^T from Vbuf[BF] */                                               \
    _Pragma("unroll")                                                                  \
    for (int dn = 0; dn < 4; ++dn) {                                                   \
      int row = dn * 32 + q31;                                                         \
      _Pragma("unroll")                                                                \
      for (int ks = 0; ks < 4; ++ks) {                                                 \
        F16_8 vf;                                                                      \
        vf.u = *(const u16x8*)&VT_lds[BF][row * 64 + ((ks * 16 + hi * 8) ^ ((row & 7) << 3))]; \
        acco[dn] = __builtin_amdgcn_mfma_f32_32x32x16_f16(vf.h, pa[ks].h, acco[dn], 0, 0, 0); \
      }                                                                                \
    }                                                                                  \
    _Pragma("unroll")                                                                  \
    for (int ks = 0; ks < 4; ++ks)                                                     \
      accl = __builtin_amdgcn_mfma_f32_32x32x16_f16(ones.h, pa[ks].h, accl, 0, 0, 0);  \
    if (t_ < NIT - 1) __syncthreads();                                                 \
  } while (0)

    for (int t = 0; t < NIT; t += 2) {
        BODY(t,     accA, accB, 0);
        BODY(t + 1, accB, accA, 1);
    }
#undef BODY

    // ---- epilogue ----
    float lv   = accl[0];
    float linv = lv > 0.f ? 1.0f / lv : 0.f;
    float* orow = O + (qrow0 + q31) * Dd;
#pragma unroll
    for (int dn = 0; dn < 4; ++dn)
#pragma unroll
        for (int rg = 0; rg < 4; ++rg) {
            f32x4 o;
            o[0] = acco[dn][rg * 4 + 0] * linv;
            o[1] = acco[dn][rg * 4 + 1] * linv;
            o[2] = acco[dn][rg * 4 + 2] * linv;
            o[3] = acco[dn][rg * 4 + 3] * linv;
            *(f32x4*)(orow + dn * 32 + rg * 8 + 4 * hi) = o;
        }
}

extern "C" void kernel_launch(void* const* d_in, const int* in_sizes, int n_in,
                              void* d_out, int out_size, void* d_ws, size_t ws_size,
                              hipStream_t stream) {
    const float* Q = (const float*)d_in[0];
    const float* K = (const float*)d_in[1];
    const float* V = (const float*)d_in[2];
    const int*   M = (const int*)d_in[3];
    float* O = (float*)d_out;
    dim3 grid(Bb * (Ss / 128));   // 512 blocks
    dim3 block(256);
    attn_fwd<<<grid, block, 0, stream>>>(Q, K, V, M, O);
}

// Round 3
// 145.497 us; speedup vs baseline: 1.8235x; 1.8235x over previous
//
#include <hip/hip_runtime.h>
#include <stdint.h>

#define Bb 32
#define Ss 2048
#define Dd 128
#define KVB 64
#define NIT (Ss / KVB)   // 32

typedef __attribute__((ext_vector_type(2))) float f32x2;
typedef __attribute__((ext_vector_type(4))) float f32x4;
typedef __attribute__((ext_vector_type(16))) float f32x16;
typedef __attribute__((ext_vector_type(8))) _Float16 f16x8;
typedef __attribute__((ext_vector_type(2))) __fp16 fp16x2;
typedef __attribute__((ext_vector_type(8))) unsigned short u16x8;
typedef __attribute__((ext_vector_type(4))) unsigned short u16x4;

union F16_8 { u16x8 u; uint32_t w[4]; f16x8 h; };
union F16_4 { u16x4 u; uint32_t w[2]; };

__device__ __forceinline__ uint32_t pk2(float a, float b) {   // packed f32->f16 RTZ
    union { fp16x2 h; uint32_t u; } v;
    v.h = __builtin_amdgcn_cvt_pkrtz(a, b);
    return v.u;
}

__global__ __launch_bounds__(256) __attribute__((amdgpu_waves_per_eu(2, 2)))
void attn_fwd(const float* __restrict__ Q,
              const float* __restrict__ K,
              const float* __restrict__ V,
              const int* __restrict__ M,
              float* __restrict__ O) {
    __shared__ unsigned short K_lds[KVB * 128];      // 16 KB, [key][d] fp16, XOR-swizzled
    __shared__ unsigned short VT_lds[2][128 * 64];   // 2x16 KB, [d][key] fp16, XOR-swizzled
    __shared__ float maskadd[KVB];

    const int tid = threadIdx.x;
    const int w   = tid >> 6;
    const int l   = tid & 63;
    const int q31 = l & 31;       // this lane's q-column (and LDS row index)
    const int hi  = l >> 5;

    const int bid   = blockIdx.x;
    const int batch = (bid & 7) * 4 + (bid >> 7);   // XCD-aware, bijective
    const int qtile = (bid >> 3) & 15;

    const size_t qrow0  = (size_t)batch * Ss + qtile * 128 + w * 32;
    const size_t kvbase = (size_t)batch * Ss * Dd;
    const size_t mbase  = (size_t)batch * Ss;

    // ---- staging geometry ----
    const int krow = tid >> 4;            // K: rows krow+16*it
    const int kcol = (tid & 15) << 3;     // K: 8 floats
    const int vi   = tid & 15;            // V: d-pair base (rows 2vi+p+32j)
    const int vk   = (tid >> 4) << 2;     // V: 4 keys

    f32x4 ka[4], kb[4];                   // K tile in flight
    f32x2 vv[4][4];                       // V tile in flight [j][ko]
    int mld = 0;

    auto issueK = [&](int kv) {
#pragma unroll
        for (int it = 0; it < 4; ++it) {
            const float* s = K + kvbase + (size_t)(kv + krow + it * 16) * Dd + kcol;
            ka[it] = *(const f32x4*)s;
            kb[it] = *(const f32x4*)(s + 4);
        }
        if (tid < KVB) mld = M[mbase + kv + tid];
    };
    auto writeK = [&]() {
#pragma unroll
        for (int it = 0; it < 4; ++it) {
            int row = krow + it * 16;
            F16_8 t;
            t.w[0] = pk2(ka[it][0], ka[it][1]);
            t.w[1] = pk2(ka[it][2], ka[it][3]);
            t.w[2] = pk2(kb[it][0], kb[it][1]);
            t.w[3] = pk2(kb[it][2], kb[it][3]);
            *(u16x8*)&K_lds[(row * 128 + kcol) ^ ((row & 7) << 3)] = t.u;
        }
        if (tid < KVB) maskadd[tid] = mld ? 0.f : -1e30f;
    };
    auto issueV = [&](int kv) {
#pragma unroll
        for (int j = 0; j < 4; ++j)
#pragma unroll
            for (int ko = 0; ko < 4; ++ko)
                vv[j][ko] = *(const f32x2*)(V + kvbase + (size_t)(kv + vk + ko) * Dd + 2 * vi + 32 * j);
    };
    auto writeV = [&](int bfi) {
#pragma unroll
        for (int j = 0; j < 4; ++j)
#pragma unroll
            for (int p = 0; p < 2; ++p) {
                int row = 2 * vi + p + 32 * j;           // row&7 varies per lane -> conflict-free
                F16_4 t;
                t.w[0] = pk2(vv[j][0][p], vv[j][1][p]);
                t.w[1] = pk2(vv[j][2][p], vv[j][3][p]);
                *(u16x4*)&VT_lds[bfi][row * 64 + (vk ^ ((row & 7) << 3))] = t.u;
            }
    };

    // ones A-fragment (rows 0..7 = 1.0) for MFMA-computed l
    F16_8 ones;
    {
        uint32_t ow = (q31 < 8) ? 0x3C003C00u : 0u;
        ones.w[0] = ow; ones.w[1] = ow; ones.w[2] = ow; ones.w[3] = ow;
    }

    const f32x16 z16 = {0,0,0,0,0,0,0,0,0,0,0,0,0,0,0,0};
    f32x16 acco[4];                       // O^T: lane owns q=q31, rows = d (crow pattern)
#pragma unroll
    for (int dn = 0; dn < 4; ++dn) acco[dn] = z16;
    f32x16 accl = z16;                    // l in element 0
    float mrun = -1e4f;

    // ---- prologue: stage tile 0; Q frags (pre-scaled by log2 e) cover the latency ----
    const float LOG2E = 1.44269504088896340736f;
    issueK(0); issueV(0);
    F16_8 qf[8];
#pragma unroll
    for (int ks = 0; ks < 8; ++ks) {
        const float* s = Q + (qrow0 + q31) * Dd + ks * 16 + hi * 8;
        f32x4 a = *(const f32x4*)s;
        f32x4 b = *(const f32x4*)(s + 4);
        qf[ks].w[0] = pk2(a[0] * LOG2E, a[1] * LOG2E);
        qf[ks].w[1] = pk2(a[2] * LOG2E, a[3] * LOG2E);
        qf[ks].w[2] = pk2(b[0] * LOG2E, b[1] * LOG2E);
        qf[ks].w[3] = pk2(b[2] * LOG2E, b[3] * LOG2E);
    }
    writeK(); writeV(0);
    __syncthreads();

    for (int t = 0; t < NIT; ++t) {
        const bool pf = (t < NIT - 1);
        // both staging loads issued at tile top: full QK+softmax covers their latency
        if (pf) { issueK((t + 1) * KVB); issueV((t + 1) * KVB); }

        // ---- S^T = K · Q^T : lane holds P^T[key crow(reg,hi)][q31] (log2 units) ----
        f32x16 accs[2];
        accs[0] = z16; accs[1] = z16;
#pragma unroll
        for (int ks = 0; ks < 8; ++ks) {
#pragma unroll
            for (int n = 0; n < 2; ++n) {
                int row = n * 32 + q31;
                F16_8 kf;
                kf.u = *(const u16x8*)&K_lds[(row * 128 + ks * 16 + hi * 8) ^ ((row & 7) << 3)];
                accs[n] = __builtin_amdgcn_mfma_f32_32x32x16_f16(kf.h, qf[ks].h, accs[n], 0, 0, 0);
            }
        }

        // ---- additive mask BEFORE max (broadcast f32x4 reads) ----
#pragma unroll
        for (int n = 0; n < 2; ++n)
#pragma unroll
            for (int blk = 0; blk < 4; ++blk) {
                f32x4 md = *(const f32x4*)&maskadd[n * 32 + blk * 8 + 4 * hi];
#pragma unroll
                for (int r = 0; r < 4; ++r) accs[n][blk * 4 + r] += md[r];
            }

        // ---- max: depth-5 tree instead of 31-deep serial chain ----
        float mx[16];
#pragma unroll
        for (int i = 0; i < 16; ++i) mx[i] = fmaxf(accs[0][i], accs[1][i]);
#pragma unroll
        for (int s = 8; s >= 1; s >>= 1)
#pragma unroll
            for (int i = 0; i < s; ++i) mx[i] = fmaxf(mx[i], mx[i + s]);
        float pmax = fmaxf(mx[0], __shfl_xor(mx[0], 32));

        // ---- online softmax, defer-max (T13); threshold 8 nats = 11.54 log2-units ----
        if (!__all(pmax - mrun <= 11.5409f)) {
            float mnew = fmaxf(mrun, pmax);
            float sc = exp2f(mrun - mnew);
#pragma unroll
            for (int dn = 0; dn < 4; ++dn)
#pragma unroll
                for (int i = 0; i < 16; ++i) acco[dn][i] *= sc;
            accl[0] *= sc;
            mrun = mnew;
        }

#pragma unroll
        for (int n = 0; n < 2; ++n)
#pragma unroll
            for (int i = 0; i < 16; ++i) accs[n][i] = exp2f(accs[n][i] - mrun);

        __syncthreads();                       // barrier 1: K_lds + maskadd reads of tile t done
        if (pf) { writeK(); writeV((t + 1) & 1); }   // V goes to idle buffer; no post-PV stall

        // ---- P^T -> B-fragments via permlane32_swap (T12) ----
        F16_8 pa[4];
#pragma unroll
        for (int ks = 0; ks < 4; ++ks) {
            int n  = ks >> 1;
            int b4 = (ks & 1) * 8;
            uint32_t x0 = pk2(accs[n][b4 + 0], accs[n][b4 + 1]);
            uint32_t x1 = pk2(accs[n][b4 + 2], accs[n][b4 + 3]);
            uint32_t y0 = pk2(accs[n][b4 + 4], accs[n][b4 + 5]);
            uint32_t y1 = pk2(accs[n][b4 + 6], accs[n][b4 + 7]);
            asm volatile("v_permlane32_swap_b32 %0, %1" : "+v"(x0), "+v"(y0));
            asm volatile("v_permlane32_swap_b32 %0, %1" : "+v"(x1), "+v"(y1));
            pa[ks].w[0] = x0;   // keys ks*16+hi*8 + {0,1}
            pa[ks].w[1] = x1;   // + {2,3}
            pa[ks].w[2] = y0;   // + {4,5}
            pa[ks].w[3] = y1;   // + {6,7}
        }

        // ---- O^T += V^T · P^T (all lane-q-local) ----
#pragma unroll
        for (int dn = 0; dn < 4; ++dn) {
            int row = dn * 32 + q31;
#pragma unroll
            for (int ks = 0; ks < 4; ++ks) {
                F16_8 vf;
                vf.u = *(const u16x8*)&VT_lds[t & 1][row * 64 + ((ks * 16 + hi * 8) ^ ((row & 7) << 3))];
                acco[dn] = __builtin_amdgcn_mfma_f32_32x32x16_f16(vf.h, pa[ks].h, acco[dn], 0, 0, 0);
            }
        }
#pragma unroll
        for (int ks = 0; ks < 4; ++ks)
            accl = __builtin_amdgcn_mfma_f32_32x32x16_f16(ones.h, pa[ks].h, accl, 0, 0, 0);

        if (pf) __syncthreads();               // barrier 2: K/V writes visible for tile t+1
    }

    // ---- epilogue ----
    float lv   = accl[0];
    float linv = lv > 0.f ? 1.0f / lv : 0.f;
    float* orow = O + (qrow0 + q31) * Dd;
#pragma unroll
    for (int dn = 0; dn < 4; ++dn)
#pragma unroll
        for (int rg = 0; rg < 4; ++rg) {
            f32x4 o;
            o[0] = acco[dn][rg * 4 + 0] * linv;
            o[1] = acco[dn][rg * 4 + 1] * linv;
            o[2] = acco[dn][rg * 4 + 2] * linv;
            o[3] = acco[dn][rg * 4 + 3] * linv;
            *(f32x4*)(orow + dn * 32 + rg * 8 + 4 * hi) = o;
        }
}

extern "C" void kernel_launch(void* const* d_in, const int* in_sizes, int n_in,
                              void* d_out, int out_size, void* d_ws, size_t ws_size,
                              hipStream_t stream) {
    const float* Q = (const float*)d_in[0];
    const float* K = (const float*)d_in[1];
    const float* V = (const float*)d_in[2];
    const int*   M = (const int*)d_in[3];
    float* O = (float*)d_out;
    dim3 grid(Bb * (Ss / 128));   // 512 blocks
    dim3 block(256);
    attn_fwd<<<grid, block, 0, stream>>>(Q, K, V, M, O);
}

// Round 4
// 116.263 us; speedup vs baseline: 2.2820x; 1.2514x over previous
//
#include <hip/hip_runtime.h>
#include <stdint.h>

#define Bb 32
#define Ss 2048
#define Dd 128
#define KVB 64
#define NIT (Ss / KVB)   // 32

typedef __attribute__((ext_vector_type(2))) float f32x2;
typedef __attribute__((ext_vector_type(4))) float f32x4;
typedef __attribute__((ext_vector_type(16))) float f32x16;
typedef __attribute__((ext_vector_type(8))) _Float16 f16x8;
typedef __attribute__((ext_vector_type(2))) __fp16 fp16x2;
typedef __attribute__((ext_vector_type(8))) unsigned short u16x8;
typedef __attribute__((ext_vector_type(4))) unsigned short u16x4;

union F16_8 { u16x8 u; uint32_t w[4]; f16x8 h; };
union F16_4 { u16x4 u; uint32_t w[2]; };

__device__ __forceinline__ uint32_t pk2(float a, float b) {   // packed f32->f16 RTZ
    union { fp16x2 h; uint32_t u; } v;
    v.h = __builtin_amdgcn_cvt_pkrtz(a, b);
    return v.u;
}

__global__ __launch_bounds__(256) __attribute__((amdgpu_waves_per_eu(2, 2)))
void attn_fwd(const float* __restrict__ Q,
              const float* __restrict__ K,
              const float* __restrict__ V,
              const int* __restrict__ M,
              float* __restrict__ O) {
    __shared__ unsigned short K_lds[KVB * 128];   // 16 KB, [key][d] fp16, XOR-swizzled
    __shared__ unsigned short VT_lds[128 * 64];   // 16 KB, [d][key] fp16, XOR-swizzled
    __shared__ float maskadd[KVB];

    const int tid = threadIdx.x;
    const int w   = tid >> 6;
    const int l   = tid & 63;
    const int q31 = l & 31;       // this lane's q-column (and LDS row index)
    const int hi  = l >> 5;

    const int bid   = blockIdx.x;
    const int batch = (bid & 7) * 4 + (bid >> 7);   // XCD-aware, bijective
    const int qtile = (bid >> 3) & 15;

    const size_t qrow0  = (size_t)batch * Ss + qtile * 128 + w * 32;
    const size_t kvbase = (size_t)batch * Ss * Dd;
    const size_t mbase  = (size_t)batch * Ss;

    // ---- staging geometry ----
    const int krow = tid >> 4;            // K: rows krow+16*it
    const int kcol = (tid & 15) << 3;     // K: 8 floats
    const int vi   = tid & 15;            // V: d-pair base (rows 2vi+p+32j)
    const int vk   = (tid >> 4) << 2;     // V: 4 keys

    f32x4 ka[4], kb[4];                   // K tile in flight
    f32x2 vv[4][4];                       // V tile in flight [j][ko]
    int mld = 0;

    auto issueK = [&](int kv) {
#pragma unroll
        for (int it = 0; it < 4; ++it) {
            const float* s = K + kvbase + (size_t)(kv + krow + it * 16) * Dd + kcol;
            ka[it] = *(const f32x4*)s;
            kb[it] = *(const f32x4*)(s + 4);
        }
        if (tid < KVB) mld = M[mbase + kv + tid];
    };
    auto writeK = [&]() {
#pragma unroll
        for (int it = 0; it < 4; ++it) {
            int row = krow + it * 16;
            F16_8 t;
            t.w[0] = pk2(ka[it][0], ka[it][1]);
            t.w[1] = pk2(ka[it][2], ka[it][3]);
            t.w[2] = pk2(kb[it][0], kb[it][1]);
            t.w[3] = pk2(kb[it][2], kb[it][3]);
            *(u16x8*)&K_lds[(row * 128 + kcol) ^ ((row & 7) << 3)] = t.u;
        }
        if (tid < KVB) maskadd[tid] = mld ? 0.f : -1e30f;
    };
    auto issueV = [&](int kv) {
#pragma unroll
        for (int j = 0; j < 4; ++j)
#pragma unroll
            for (int ko = 0; ko < 4; ++ko)
                vv[j][ko] = *(const f32x2*)(V + kvbase + (size_t)(kv + vk + ko) * Dd + 2 * vi + 32 * j);
    };
    auto writeV = [&]() {
#pragma unroll
        for (int j = 0; j < 4; ++j)
#pragma unroll
            for (int p = 0; p < 2; ++p) {
                int row = 2 * vi + p + 32 * j;           // row&7 varies per lane -> conflict-free
                F16_4 t;
                t.w[0] = pk2(vv[j][0][p], vv[j][1][p]);
                t.w[1] = pk2(vv[j][2][p], vv[j][3][p]);
                *(u16x4*)&VT_lds[row * 64 + (vk ^ ((row & 7) << 3))] = t.u;
            }
    };

    // ones A-fragment (rows 0..7 = 1.0) for MFMA-computed l
    F16_8 ones;
    {
        uint32_t ow = (q31 < 8) ? 0x3C003C00u : 0u;
        ones.w[0] = ow; ones.w[1] = ow; ones.w[2] = ow; ones.w[3] = ow;
    }

    const f32x16 z16 = {0,0,0,0,0,0,0,0,0,0,0,0,0,0,0,0};
    f32x16 acco[4];                       // O^T: lane owns q=q31, rows = d (crow pattern)
#pragma unroll
    for (int dn = 0; dn < 4; ++dn) acco[dn] = z16;
    f32x16 accl = z16;                    // l in element 0
    float mrun = -1e4f;

    // ---- prologue: stage tile 0; Q frags (pre-scaled by log2 e) cover the latency ----
    const float LOG2E = 1.44269504088896340736f;
    issueK(0); issueV(0);
    F16_8 qf[8];
#pragma unroll
    for (int ks = 0; ks < 8; ++ks) {
        const float* s = Q + (qrow0 + q31) * Dd + ks * 16 + hi * 8;
        f32x4 a = *(const f32x4*)s;
        f32x4 b = *(const f32x4*)(s + 4);
        qf[ks].w[0] = pk2(a[0] * LOG2E, a[1] * LOG2E);
        qf[ks].w[1] = pk2(a[2] * LOG2E, a[3] * LOG2E);
        qf[ks].w[2] = pk2(b[0] * LOG2E, b[1] * LOG2E);
        qf[ks].w[3] = pk2(b[2] * LOG2E, b[3] * LOG2E);
    }
    writeK(); writeV();
    __syncthreads();

    for (int t = 0; t < NIT; ++t) {
        if (t < NIT - 1) issueK((t + 1) * KVB);    // hides under QK+softmax

        // ---- S^T = K · Q^T : lane holds P^T[key crow(reg,hi)][q31] (log2 units) ----
        f32x16 accs[2];
        accs[0] = z16; accs[1] = z16;
#pragma unroll
        for (int ks = 0; ks < 8; ++ks) {
#pragma unroll
            for (int n = 0; n < 2; ++n) {
                int row = n * 32 + q31;
                F16_8 kf;
                kf.u = *(const u16x8*)&K_lds[(row * 128 + ks * 16 + hi * 8) ^ ((row & 7) << 3)];
                accs[n] = __builtin_amdgcn_mfma_f32_32x32x16_f16(kf.h, qf[ks].h, accs[n], 0, 0, 0);
            }
        }

        // ---- additive mask BEFORE max (broadcast f32x4 reads) ----
#pragma unroll
        for (int n = 0; n < 2; ++n)
#pragma unroll
            for (int blk = 0; blk < 4; ++blk) {
                f32x4 md = *(const f32x4*)&maskadd[n * 32 + blk * 8 + 4 * hi];
#pragma unroll
                for (int r = 0; r < 4; ++r) accs[n][blk * 4 + r] += md[r];
            }

        // ---- max: depth-5 tree instead of 31-deep serial chain ----
        float mx[16];
#pragma unroll
        for (int i = 0; i < 16; ++i) mx[i] = fmaxf(accs[0][i], accs[1][i]);
#pragma unroll
        for (int s = 8; s >= 1; s >>= 1)
#pragma unroll
            for (int i = 0; i < s; ++i) mx[i] = fmaxf(mx[i], mx[i + s]);
        float pmax = fmaxf(mx[0], __shfl_xor(mx[0], 32));

        // ---- online softmax, defer-max (T13); threshold 8 nats = 11.54 log2-units ----
        if (!__all(pmax - mrun <= 11.5409f)) {
            float mnew = fmaxf(mrun, pmax);
            float sc = exp2f(mrun - mnew);
#pragma unroll
            for (int dn = 0; dn < 4; ++dn)
#pragma unroll
                for (int i = 0; i < 16; ++i) acco[dn][i] *= sc;
            accl[0] *= sc;
            mrun = mnew;
        }

#pragma unroll
        for (int n = 0; n < 2; ++n)
#pragma unroll
            for (int i = 0; i < 16; ++i) accs[n][i] = exp2f(accs[n][i] - mrun);

        // ---- P^T -> B-fragments via permlane32_swap (T12) ----
        F16_8 pa[4];
#pragma unroll
        for (int ks = 0; ks < 4; ++ks) {
            int n  = ks >> 1;
            int b4 = (ks & 1) * 8;
            uint32_t x0 = pk2(accs[n][b4 + 0], accs[n][b4 + 1]);
            uint32_t x1 = pk2(accs[n][b4 + 2], accs[n][b4 + 3]);
            uint32_t y0 = pk2(accs[n][b4 + 4], accs[n][b4 + 5]);
            uint32_t y1 = pk2(accs[n][b4 + 6], accs[n][b4 + 7]);
            asm volatile("v_permlane32_swap_b32 %0, %1" : "+v"(x0), "+v"(y0));
            asm volatile("v_permlane32_swap_b32 %0, %1" : "+v"(x1), "+v"(y1));
            pa[ks].w[0] = x0;   // keys ks*16+hi*8 + {0,1}
            pa[ks].w[1] = x1;   // + {2,3}
            pa[ks].w[2] = y0;   // + {4,5}
            pa[ks].w[3] = y1;   // + {6,7}
        }

        __syncthreads();                       // K_lds + maskadd reads of tile t done
        if (t < NIT - 1) { writeK(); issueV((t + 1) * KVB); }

        // ---- O^T += V^T · P^T (all lane-q-local) ----
#pragma unroll
        for (int dn = 0; dn < 4; ++dn) {
            int row = dn * 32 + q31;
#pragma unroll
            for (int ks = 0; ks < 4; ++ks) {
                F16_8 vf;
                vf.u = *(const u16x8*)&VT_lds[row * 64 + ((ks * 16 + hi * 8) ^ ((row & 7) << 3))];
                acco[dn] = __builtin_amdgcn_mfma_f32_32x32x16_f16(vf.h, pa[ks].h, acco[dn], 0, 0, 0);
            }
        }
#pragma unroll
        for (int ks = 0; ks < 4; ++ks)
            accl = __builtin_amdgcn_mfma_f32_32x32x16_f16(ones.h, pa[ks].h, accl, 0, 0, 0);

        __syncthreads();                       // VT_lds reads of tile t done
        if (t < NIT - 1) writeV();
    }

    // ---- epilogue ----
    float lv   = accl[0];
    float linv = lv > 0.f ? 1.0f / lv : 0.f;
    float* orow = O + (qrow0 + q31) * Dd;
#pragma unroll
    for (int dn = 0; dn < 4; ++dn)
#pragma unroll
        for (int rg = 0; rg < 4; ++rg) {
            f32x4 o;
            o[0] = acco[dn][rg * 4 + 0] * linv;
            o[1] = acco[dn][rg * 4 + 1] * linv;
            o[2] = acco[dn][rg * 4 + 2] * linv;
            o[3] = acco[dn][rg * 4 + 3] * linv;
            *(f32x4*)(orow + dn * 32 + rg * 8 + 4 * hi) = o;
        }
}

extern "C" void kernel_launch(void* const* d_in, const int* in_sizes, int n_in,
                              void* d_out, int out_size, void* d_ws, size_t ws_size,
                              hipStream_t stream) {
    const float* Q = (const float*)d_in[0];
    const float* K = (const float*)d_in[1];
    const float* V = (const float*)d_in[2];
    const int*   M = (const int*)d_in[3];
    float* O = (float*)d_out;
    dim3 grid(Bb * (Ss / 128));   // 512 blocks
    dim3 block(256);
    attn_fwd<<<grid, block, 0, stream>>>(Q, K, V, M, O);
}

// Round 5
// 106.162 us; speedup vs baseline: 2.4992x; 1.0951x over previous
//
#include <hip/hip_runtime.h>
#include <stdint.h>

#define Bb 32
#define Ss 2048
#define Dd 128
#define KVB 64
#define NIT (Ss / KVB)   // 32

typedef __attribute__((ext_vector_type(2))) float f32x2;
typedef __attribute__((ext_vector_type(4))) float f32x4;
typedef __attribute__((ext_vector_type(16))) float f32x16;
typedef __attribute__((ext_vector_type(8))) _Float16 f16x8;
typedef __attribute__((ext_vector_type(2))) __fp16 fp16x2;
typedef __attribute__((ext_vector_type(8))) unsigned short u16x8;
typedef __attribute__((ext_vector_type(4))) unsigned short u16x4;

union F16_8 { u16x8 u; uint32_t w[4]; f16x8 h; };
union F16_4 { u16x4 u; uint32_t w[2]; };

__device__ __forceinline__ uint32_t pk2(float a, float b) {   // packed f32->f16 RTZ
    union { fp16x2 h; uint32_t u; } v;
    v.h = __builtin_amdgcn_cvt_pkrtz(a, b);
    return v.u;
}

__global__ __launch_bounds__(256) __attribute__((amdgpu_waves_per_eu(2, 2)))
void attn_fwd(const float* __restrict__ Q,
              const float* __restrict__ K,
              const float* __restrict__ V,
              const int* __restrict__ M,
              float* __restrict__ O) {
    __shared__ unsigned short K_lds[KVB * 128];   // 16 KB, [key][d] fp16, XOR-swizzled
    __shared__ unsigned short VT_lds[128 * 64];   // 16 KB, [d][key] fp16, XOR-swizzled
    __shared__ float maskadd[KVB];

    const int tid = threadIdx.x;
    const int w   = tid >> 6;
    const int l   = tid & 63;
    const int q31 = l & 31;       // this lane's q-column (and LDS row index)
    const int hi  = l >> 5;

    const int bid   = blockIdx.x;
    const int batch = (bid & 7) * 4 + (bid >> 7);   // XCD-aware, bijective
    const int qtile = (bid >> 3) & 15;

    const size_t qrow0  = (size_t)batch * Ss + qtile * 128 + w * 32;
    const size_t kvbase = (size_t)batch * Ss * Dd;
    const size_t mbase  = (size_t)batch * Ss;

    // ---- staging geometry ----
    const int krow = tid >> 4;            // K: rows krow+16*it
    const int kcol = (tid & 15) << 3;     // K: 8 floats
    const int vi   = tid & 15;            // V: d-pair base (rows 2vi+p+32j)
    const int vk   = (tid >> 4) << 2;     // V: 4 keys

    f32x4 ka[4], kb[4];                   // K tile in flight
    f32x2 vv[4][4];                       // V tile in flight [j][ko]
    int mld = 0;

    auto issueK = [&](int kv) {
#pragma unroll
        for (int it = 0; it < 4; ++it) {
            const float* s = K + kvbase + (size_t)(kv + krow + it * 16) * Dd + kcol;
            ka[it] = *(const f32x4*)s;
            kb[it] = *(const f32x4*)(s + 4);
        }
        if (tid < KVB) mld = M[mbase + kv + tid];
    };
    auto writeK = [&]() {
#pragma unroll
        for (int it = 0; it < 4; ++it) {
            int row = krow + it * 16;
            F16_8 t;
            t.w[0] = pk2(ka[it][0], ka[it][1]);
            t.w[1] = pk2(ka[it][2], ka[it][3]);
            t.w[2] = pk2(kb[it][0], kb[it][1]);
            t.w[3] = pk2(kb[it][2], kb[it][3]);
            *(u16x8*)&K_lds[(row * 128 + kcol) ^ ((row & 7) << 3)] = t.u;
        }
        if (tid < KVB) maskadd[tid] = mld ? 0.f : -1e30f;
    };
    auto issueV = [&](int kv) {
#pragma unroll
        for (int j = 0; j < 4; ++j)
#pragma unroll
            for (int ko = 0; ko < 4; ++ko)
                vv[j][ko] = *(const f32x2*)(V + kvbase + (size_t)(kv + vk + ko) * Dd + 2 * vi + 32 * j);
    };
    auto writeV = [&]() {
#pragma unroll
        for (int j = 0; j < 4; ++j)
#pragma unroll
            for (int p = 0; p < 2; ++p) {
                int row = 2 * vi + p + 32 * j;           // row&7 varies per lane -> conflict-free
                F16_4 t;
                t.w[0] = pk2(vv[j][0][p], vv[j][1][p]);
                t.w[1] = pk2(vv[j][2][p], vv[j][3][p]);
                *(u16x4*)&VT_lds[row * 64 + (vk ^ ((row & 7) << 3))] = t.u;
            }
    };

    // ones A-fragment (rows 0..7 = 1.0) for MFMA-computed l
    F16_8 ones;
    {
        uint32_t ow = (q31 < 8) ? 0x3C003C00u : 0u;
        ones.w[0] = ow; ones.w[1] = ow; ones.w[2] = ow; ones.w[3] = ow;
    }

    const f32x16 z16 = {0,0,0,0,0,0,0,0,0,0,0,0,0,0,0,0};
    f32x16 acco[4];                       // O^T: lane owns q=q31, rows = d (crow pattern)
#pragma unroll
    for (int dn = 0; dn < 4; ++dn) acco[dn] = z16;
    f32x16 accl = z16;                    // l in element 0
    float mrun = -1e4f;

    // ---- prologue: stage tile 0; Q frags (pre-scaled by log2 e) cover the latency ----
    const float LOG2E = 1.44269504088896340736f;
    issueK(0); issueV(0);
    F16_8 qf[8];
#pragma unroll
    for (int ks = 0; ks < 8; ++ks) {
        const float* s = Q + (qrow0 + q31) * Dd + ks * 16 + hi * 8;
        f32x4 a = *(const f32x4*)s;
        f32x4 b = *(const f32x4*)(s + 4);
        qf[ks].w[0] = pk2(a[0] * LOG2E, a[1] * LOG2E);
        qf[ks].w[1] = pk2(a[2] * LOG2E, a[3] * LOG2E);
        qf[ks].w[2] = pk2(b[0] * LOG2E, b[1] * LOG2E);
        qf[ks].w[3] = pk2(b[2] * LOG2E, b[3] * LOG2E);
    }
    writeK(); writeV();
    __syncthreads();

    for (int t = 0; t < NIT; ++t) {
        if (t < NIT - 1) issueK((t + 1) * KVB);    // hides under QK+softmax

        // ---- S^T = K · Q^T : lane holds P^T[key crow(reg,hi)][q31] (log2 units) ----
        f32x16 accs[2];
        accs[0] = z16; accs[1] = z16;
#pragma unroll
        for (int ks = 0; ks < 8; ++ks) {
#pragma unroll
            for (int n = 0; n < 2; ++n) {
                int row = n * 32 + q31;
                F16_8 kf;
                kf.u = *(const u16x8*)&K_lds[(row * 128 + ks * 16 + hi * 8) ^ ((row & 7) << 3)];
                accs[n] = __builtin_amdgcn_mfma_f32_32x32x16_f16(kf.h, qf[ks].h, accs[n], 0, 0, 0);
            }
        }

        // ---- additive mask BEFORE max (broadcast f32x4 reads) ----
#pragma unroll
        for (int n = 0; n < 2; ++n)
#pragma unroll
            for (int blk = 0; blk < 4; ++blk) {
                f32x4 md = *(const f32x4*)&maskadd[n * 32 + blk * 8 + 4 * hi];
#pragma unroll
                for (int r = 0; r < 4; ++r) accs[n][blk * 4 + r] += md[r];
            }

        // ---- max: depth-5 tree ----
        float mx[16];
#pragma unroll
        for (int i = 0; i < 16; ++i) mx[i] = fmaxf(accs[0][i], accs[1][i]);
#pragma unroll
        for (int s = 8; s >= 1; s >>= 1)
#pragma unroll
            for (int i = 0; i < s; ++i) mx[i] = fmaxf(mx[i], mx[i + s]);
        float pmax = fmaxf(mx[0], __shfl_xor(mx[0], 32));

        // ---- online softmax, defer-max (T13); threshold 8 nats = 11.54 log2-units ----
        if (!__all(pmax - mrun <= 11.5409f)) {
            float mnew = fmaxf(mrun, pmax);
            float sc = __builtin_amdgcn_exp2f(mrun - mnew);
#pragma unroll
            for (int dn = 0; dn < 4; ++dn)
#pragma unroll
                for (int i = 0; i < 16; ++i) acco[dn][i] *= sc;
            accl[0] *= sc;
            mrun = mnew;
        }

#pragma unroll
        for (int n = 0; n < 2; ++n)
#pragma unroll
            for (int i = 0; i < 16; ++i) accs[n][i] = __builtin_amdgcn_exp2f(accs[n][i] - mrun);

        // ---- P^T -> B-fragments via permlane32_swap (T12) ----
        F16_8 pa[4];
#pragma unroll
        for (int ks = 0; ks < 4; ++ks) {
            int n  = ks >> 1;
            int b4 = (ks & 1) * 8;
            uint32_t x0 = pk2(accs[n][b4 + 0], accs[n][b4 + 1]);
            uint32_t x1 = pk2(accs[n][b4 + 2], accs[n][b4 + 3]);
            uint32_t y0 = pk2(accs[n][b4 + 4], accs[n][b4 + 5]);
            uint32_t y1 = pk2(accs[n][b4 + 6], accs[n][b4 + 7]);
            asm volatile("v_permlane32_swap_b32 %0, %1" : "+v"(x0), "+v"(y0));
            asm volatile("v_permlane32_swap_b32 %0, %1" : "+v"(x1), "+v"(y1));
            pa[ks].w[0] = x0;   // keys ks*16+hi*8 + {0,1}
            pa[ks].w[1] = x1;   // + {2,3}
            pa[ks].w[2] = y0;   // + {4,5}
            pa[ks].w[3] = y1;   // + {6,7}
        }

        __syncthreads();                       // K_lds + maskadd reads of tile t done
        if (t < NIT - 1) { writeK(); issueV((t + 1) * KVB); }

        // ---- O^T += V^T · P^T (all lane-q-local) ----
#pragma unroll
        for (int dn = 0; dn < 4; ++dn) {
            int row = dn * 32 + q31;
#pragma unroll
            for (int ks = 0; ks < 4; ++ks) {
                F16_8 vf;
                vf.u = *(const u16x8*)&VT_lds[row * 64 + ((ks * 16 + hi * 8) ^ ((row & 7) << 3))];
                acco[dn] = __builtin_amdgcn_mfma_f32_32x32x16_f16(vf.h, pa[ks].h, acco[dn], 0, 0, 0);
            }
        }
#pragma unroll
        for (int ks = 0; ks < 4; ++ks)
            accl = __builtin_amdgcn_mfma_f32_32x32x16_f16(ones.h, pa[ks].h, accl, 0, 0, 0);

        __syncthreads();                       // VT_lds reads of tile t done
        if (t < NIT - 1) writeV();
    }

    // ---- epilogue ----
    float lv   = accl[0];
    float linv = lv > 0.f ? 1.0f / lv : 0.f;
    float* orow = O + (qrow0 + q31) * Dd;
#pragma unroll
    for (int dn = 0; dn < 4; ++dn)
#pragma unroll
        for (int rg = 0; rg < 4; ++rg) {
            f32x4 o;
            o[0] = acco[dn][rg * 4 + 0] * linv;
            o[1] = acco[dn][rg * 4 + 1] * linv;
            o[2] = acco[dn][rg * 4 + 2] * linv;
            o[3] = acco[dn][rg * 4 + 3] * linv;
            *(f32x4*)(orow + dn * 32 + rg * 8 + 4 * hi) = o;
        }
}

extern "C" void kernel_launch(void* const* d_in, const int* in_sizes, int n_in,
                              void* d_out, int out_size, void* d_ws, size_t ws_size,
                              hipStream_t stream) {
    const float* Q = (const float*)d_in[0];
    const float* K = (const float*)d_in[1];
    const float* V = (const float*)d_in[2];
    const int*   M = (const int*)d_in[3];
    float* O = (float*)d_out;
    dim3 grid(Bb * (Ss / 128));   // 512 blocks
    dim3 block(256);
    attn_fwd<<<grid, block, 0, stream>>>(Q, K, V, M, O);
}